// Round 3
// baseline (529.797 us; speedup 1.0000x reference)
//
#include <hip/hip_runtime.h>
#include <hip/hip_bf16.h>

#define DM   1024
#define NE   8
#define DFF  4096
#define NTOK 4096

typedef __attribute__((ext_vector_type(8))) short bf16x8;
typedef __attribute__((ext_vector_type(4))) float f32x4;

__device__ __forceinline__ short to_bf16(float f) {
  unsigned u = __float_as_uint(f);
  unsigned r = (u + 0x7fffu + ((u >> 16) & 1u)) >> 16;   // RNE
  return (short)r;
}

__device__ __forceinline__ void gl16(const void* g, void* l) {
  __builtin_amdgcn_global_load_lds(
      (const __attribute__((address_space(1))) unsigned*)g,
      (__attribute__((address_space(3))) unsigned*)l, 16, 0, 0);
}

// ---------------- router ----------------
__global__ __launch_bounds__(256) void router_kernel(
    const float* __restrict__ x, const float* __restrict__ gw,
    int* __restrict__ cnt, float* __restrict__ psum,
    int* __restrict__ pairs, float* __restrict__ pairW)
{
  __shared__ float gws[DM * NE];
  const int tid = threadIdx.x;
  for (int i = tid * 4; i < DM * NE; i += 256 * 4)
    *reinterpret_cast<float4*>(&gws[i]) = *reinterpret_cast<const float4*>(&gw[i]);
  __syncthreads();

  const int n = blockIdx.x * 256 + tid;
  float acc[NE];
#pragma unroll
  for (int e = 0; e < NE; ++e) acc[e] = 0.f;

  const float4* xr = reinterpret_cast<const float4*>(x + (size_t)n * DM);
  for (int d4 = 0; d4 < DM / 4; ++d4) {
    float4 v = xr[d4];
    const float* gp = &gws[d4 * 4 * NE];
    float xv;
#pragma unroll
    for (int dd = 0; dd < 4; ++dd) {
      xv = (dd == 0) ? v.x : (dd == 1) ? v.y : (dd == 2) ? v.z : v.w;
#pragma unroll
      for (int e = 0; e < NE; ++e) acc[e] = fmaf(xv, gp[dd * NE + e], acc[e]);
    }
  }

  float mx = acc[0];
#pragma unroll
  for (int e = 1; e < NE; ++e) mx = fmaxf(mx, acc[e]);
  float p[NE], s = 0.f;
#pragma unroll
  for (int e = 0; e < NE; ++e) { p[e] = expf(acc[e] - mx); s += p[e]; }
  float inv = 1.f / s;
#pragma unroll
  for (int e = 0; e < NE; ++e) {
    float v = p[e] * inv;
#pragma unroll
    for (int o = 32; o > 0; o >>= 1) v += __shfl_xor(v, o);
    if ((tid & 63) == 0) atomicAdd(&psum[e], v);
  }

  float v0 = -1e30f, v1 = -1e30f; int i0 = 0, i1 = 0;
#pragma unroll
  for (int e = 0; e < NE; ++e) {
    float l = acc[e];
    if (l > v0) { v1 = v0; i1 = i0; v0 = l; i0 = e; }
    else if (l > v1) { v1 = l; i1 = e; }
  }
  float e1 = expf(v1 - v0);
  float den = 1.f + e1;
  pairW[n * 2]     = 1.f / den;
  pairW[n * 2 + 1] = e1 / den;
  int p0 = atomicAdd(&cnt[i0], 1); pairs[i0 * NTOK + p0] = n * 2;
  int p1 = atomicAdd(&cnt[i1], 1); pairs[i1 * NTOK + p1] = n * 2 + 1;
}

__global__ void finalize_kernel(const int* __restrict__ cnt, int* __restrict__ off,
                                const float* __restrict__ psum, float* __restrict__ aux)
{
  if (threadIdx.x == 0 && blockIdx.x == 0) {
    int o = 0;
    for (int e = 0; e < NE; ++e) { off[e] = o; o += cnt[e]; }
    off[NE] = o;
    float a = 0.f;
    for (int e = 0; e < NE; ++e) { float me = psum[e] * (1.f / NTOK); a += me * me; }
    aux[0] = a * (float)NE;
  }
}

// ---------------- prepass: x f32 -> bf16 ----------------
__global__ __launch_bounds__(256) void convert_x_kernel(
    const float* __restrict__ x, short* __restrict__ xb)
{
  const int i = (blockIdx.x * 256 + threadIdx.x) * 8;
  float4 a = *reinterpret_cast<const float4*>(&x[i]);
  float4 b = *reinterpret_cast<const float4*>(&x[i + 4]);
  union { short s[8]; bf16x8 v; } p;
  p.s[0]=to_bf16(a.x); p.s[1]=to_bf16(a.y); p.s[2]=to_bf16(a.z); p.s[3]=to_bf16(a.w);
  p.s[4]=to_bf16(b.x); p.s[5]=to_bf16(b.y); p.s[6]=to_bf16(b.z); p.s[7]=to_bf16(b.w);
  *reinterpret_cast<bf16x8*>(&xb[i]) = p.v;
}

// ---------------- prepass: transpose + convert weights ----------------
__global__ __launch_bounds__(256) void transpose_kernel(
    const float* __restrict__ w1, const float* __restrict__ w2,
    short* __restrict__ w1t, short* __restrict__ w2t)
{
  const int z = blockIdx.z;
  const float* src; short* dst; int R, C, rt, ct;
  if (z < 8) { src = w1 + (size_t)z * DM * DFF; dst = w1t + (size_t)z * DM * DFF;
               R = DM; C = DFF; ct = blockIdx.x; rt = blockIdx.y; }
  else       { src = w2 + (size_t)(z - 8) * DM * DFF; dst = w2t + (size_t)(z - 8) * DM * DFF;
               R = DFF; C = DM; ct = blockIdx.y; rt = blockIdx.x; }
  const int r0 = rt * 64, c0 = ct * 64;
  __shared__ float t[64][65];
  const int tid = threadIdx.x;
  {
    const int row = tid >> 4;
    const int col = (tid & 15) * 4;
#pragma unroll
    for (int it = 0; it < 4; ++it) {
      float4 v = *reinterpret_cast<const float4*>(&src[(size_t)(r0 + it * 16 + row) * C + c0 + col]);
      t[it * 16 + row][col]     = v.x;
      t[it * 16 + row][col + 1] = v.y;
      t[it * 16 + row][col + 2] = v.z;
      t[it * 16 + row][col + 3] = v.w;
    }
  }
  __syncthreads();
  {
    const int oc  = tid >> 3;
    const int orr = (tid & 7) * 8;
#pragma unroll
    for (int it = 0; it < 2; ++it) {
      union { short s[8]; bf16x8 v; } p;
#pragma unroll
      for (int j = 0; j < 8; ++j) p.s[j] = to_bf16(t[orr + j][it * 32 + oc]);
      *reinterpret_cast<bf16x8*>(&dst[(size_t)(c0 + it * 32 + oc) * R + r0 + orr]) = p.v;
    }
  }
}

// ======== GEMM1: h = gelu(gather(xb) @ w1t[e]^T), 256x256xBK64 2ph dbuf ========
__global__ __launch_bounds__(512) void gemm1_kernel(
    const short* __restrict__ xb, const short* __restrict__ w1t,
    const int* __restrict__ cnt, const int* __restrict__ off,
    const int* __restrict__ pairs, short* __restrict__ h)
{
  // bijective XCD swizzle, nwg=2048; decode: m inner(16), e mid(8), ff outer(16)
  const int wg = (blockIdx.x & 7) * 256 + (blockIdx.x >> 3);
  const int mt = wg & 15;
  const int e  = (wg >> 4) & 7;
  const int ft = wg >> 7;
  const int M  = cnt[e];
  const int m0 = mt * 256;
  if (m0 >= M) return;
  const int ff0  = ft * 256;
  const int base = off[e];

  __shared__ __attribute__((aligned(16))) short As[2][256 * 64];
  __shared__ __attribute__((aligned(16))) short Bs[2][256 * 64];

  const int tid  = threadIdx.x;
  const int lane = tid & 63;
  const int wv   = tid >> 6;
  const int wm   = wv >> 2;   // 0..1
  const int wn   = wv & 3;    // 0..3

  // staging: round r covers rows r*64..r*64+63; source pre-swizzled (chunk ^= row&7)
  const int srow = tid >> 3;                            // 0..63
  const int sswz = ((tid & 7) ^ (srow & 7)) * 8;        // shorts
  const short* gA[4]; const short* gB[4];
#pragma unroll
  for (int r = 0; r < 4; ++r) {
    const int row = r * 64 + srow;
    int gi = m0 + row; if (gi > M - 1) gi = M - 1;
    const int tok = pairs[e * NTOK + gi] >> 1;
    gA[r] = xb + (size_t)tok * DM + sswz;
    gB[r] = w1t + ((size_t)e * DFF + ff0 + row) * DM + sswz;
  }

#define STAGE1(buf, k0) do { \
  _Pragma("unroll") for (int r = 0; r < 4; ++r) gl16(gA[r] + (k0), &As[buf][r * 4096 + wv * 512]); \
  _Pragma("unroll") for (int r = 0; r < 4; ++r) gl16(gB[r] + (k0), &Bs[buf][r * 4096 + wv * 512]); \
} while (0)

  // frag-read offsets: swizzled chunk = (c*4 + lane>>4) ^ (lane&7)
  int cro[2];
#pragma unroll
  for (int c = 0; c < 2; ++c)
    cro[c] = (((c * 4 + (lane >> 4)) ^ (lane & 7)) << 3);
  const int arow0 = wm * 128 + (lane & 15);
  const int brow0 = wn * 64  + (lane & 15);

  f32x4 acc[8][4];
#pragma unroll
  for (int i = 0; i < 8; ++i)
#pragma unroll
    for (int j = 0; j < 4; ++j) acc[i][j] = (f32x4){0.f, 0.f, 0.f, 0.f};

  STAGE1(0, 0);
  __syncthreads();

  for (int t = 0; t < 16; ++t) {
    const int cur = t & 1;
    if (t < 15) STAGE1(cur ^ 1, (t + 1) * 64);
#pragma unroll
    for (int c = 0; c < 2; ++c) {
      bf16x8 af[8], bfv[4];
#pragma unroll
      for (int i = 0; i < 8; ++i)
        af[i] = *reinterpret_cast<const bf16x8*>(&As[cur][(arow0 + i * 16) * 64 + cro[c]]);
#pragma unroll
      for (int j = 0; j < 4; ++j)
        bfv[j] = *reinterpret_cast<const bf16x8*>(&Bs[cur][(brow0 + j * 16) * 64 + cro[c]]);
#pragma unroll
      for (int i = 0; i < 8; ++i)
#pragma unroll
        for (int j = 0; j < 4; ++j)
          acc[i][j] = __builtin_amdgcn_mfma_f32_16x16x32_bf16(af[i], bfv[j], acc[i][j], 0, 0, 0);
    }
    __syncthreads();
  }

  const int erow0 = m0 + wm * 128 + (lane >> 4) * 4;
  const int ecol0 = ff0 + wn * 64 + (lane & 15);
#pragma unroll
  for (int i = 0; i < 8; ++i) {
#pragma unroll
    for (int r = 0; r < 4; ++r) {
      const int grow = erow0 + i * 16 + r;
      if (grow < M) {
#pragma unroll
        for (int j = 0; j < 4; ++j) {
          float v = acc[i][j][r];
          float g = 0.5f * v * (1.f + erff(v * 0.70710678118f));
          h[(size_t)(base + grow) * DFF + ecol0 + j * 16] = to_bf16(g);
        }
      }
    }
  }
#undef STAGE1
}

// ======== GEMM2: out += w * (h @ w2t[e]^T), 256x256, split-K=2, 2ph dbuf ========
__global__ __launch_bounds__(512) void gemm2_kernel(
    const short* __restrict__ h, const short* __restrict__ w2t,
    const int* __restrict__ cnt, const int* __restrict__ off,
    const int* __restrict__ pairs, const float* __restrict__ pairW,
    float* __restrict__ out)
{
  // nwg=1024; decode: m inner(16), e mid(8), (d,kh) outer(8)
  const int wg = (blockIdx.x & 7) * 128 + (blockIdx.x >> 3);
  const int mt = wg & 15;
  const int e  = (wg >> 4) & 7;
  const int z  = wg >> 7;         // 0..7
  const int dt = z & 3;
  const int kh = z >> 2;          // 0..1
  const int M  = cnt[e];
  const int m0 = mt * 256;
  if (m0 >= M) return;
  const int d0    = dt * 256;
  const int kbase = kh * 2048;
  const int base  = off[e];

  __shared__ __attribute__((aligned(16))) short As[2][256 * 64];
  __shared__ __attribute__((aligned(16))) short Bs[2][256 * 64];

  const int tid  = threadIdx.x;
  const int lane = tid & 63;
  const int wv   = tid >> 6;
  const int wm   = wv >> 2;
  const int wn   = wv & 3;

  const int srow = tid >> 3;
  const int sswz = ((tid & 7) ^ (srow & 7)) * 8;
  const short* gA[4]; const short* gB[4];
#pragma unroll
  for (int r = 0; r < 4; ++r) {
    const int row = r * 64 + srow;
    int gi = m0 + row; if (gi > M - 1) gi = M - 1;
    gA[r] = h + (size_t)(base + gi) * DFF + kbase + sswz;
    gB[r] = w2t + ((size_t)e * DM + d0 + row) * DFF + kbase + sswz;
  }

#define STAGE2(buf, k0) do { \
  _Pragma("unroll") for (int r = 0; r < 4; ++r) gl16(gA[r] + (k0), &As[buf][r * 4096 + wv * 512]); \
  _Pragma("unroll") for (int r = 0; r < 4; ++r) gl16(gB[r] + (k0), &Bs[buf][r * 4096 + wv * 512]); \
} while (0)

  int cro[2];
#pragma unroll
  for (int c = 0; c < 2; ++c)
    cro[c] = (((c * 4 + (lane >> 4)) ^ (lane & 7)) << 3);
  const int arow0 = wm * 128 + (lane & 15);
  const int brow0 = wn * 64  + (lane & 15);

  f32x4 acc[8][4];
#pragma unroll
  for (int i = 0; i < 8; ++i)
#pragma unroll
    for (int j = 0; j < 4; ++j) acc[i][j] = (f32x4){0.f, 0.f, 0.f, 0.f};

  STAGE2(0, 0);
  __syncthreads();

  for (int t = 0; t < 32; ++t) {
    const int cur = t & 1;
    if (t < 31) STAGE2(cur ^ 1, (t + 1) * 64);
#pragma unroll
    for (int c = 0; c < 2; ++c) {
      bf16x8 af[8], bfv[4];
#pragma unroll
      for (int i = 0; i < 8; ++i)
        af[i] = *reinterpret_cast<const bf16x8*>(&As[cur][(arow0 + i * 16) * 64 + cro[c]]);
#pragma unroll
      for (int j = 0; j < 4; ++j)
        bfv[j] = *reinterpret_cast<const bf16x8*>(&Bs[cur][(brow0 + j * 16) * 64 + cro[c]]);
#pragma unroll
      for (int i = 0; i < 8; ++i)
#pragma unroll
        for (int j = 0; j < 4; ++j)
          acc[i][j] = __builtin_amdgcn_mfma_f32_16x16x32_bf16(af[i], bfv[j], acc[i][j], 0, 0, 0);
    }
    __syncthreads();
  }

  const int erow0 = m0 + wm * 128 + (lane >> 4) * 4;
  const int ecol0 = d0 + wn * 64 + (lane & 15);
#pragma unroll
  for (int i = 0; i < 8; ++i) {
#pragma unroll
    for (int r = 0; r < 4; ++r) {
      const int grow = erow0 + i * 16 + r;
      if (grow < M) {
        const int pr    = pairs[e * NTOK + grow];
        const float wgt = pairW[pr];
        const int tok   = pr >> 1;
#pragma unroll
        for (int j = 0; j < 4; ++j)
          atomicAdd(&out[(size_t)tok * DM + ecol0 + j * 16], wgt * acc[i][j][r]);
      }
    }
  }
#undef STAGE2
}

extern "C" void kernel_launch(void* const* d_in, const int* in_sizes, int n_in,
                              void* d_out, int out_size, void* d_ws, size_t ws_size,
                              hipStream_t stream)
{
  const float* x  = (const float*)d_in[0];
  const float* gw = (const float*)d_in[1];
  const float* w1 = (const float*)d_in[2];
  const float* w2 = (const float*)d_in[3];
  float* outf = (float*)d_out;

  int*   cnt   = (int*)d_ws;
  int*   off   = cnt + 8;
  float* psum  = (float*)(cnt + 20);
  int*   pairs = (int*)((char*)d_ws + 512);
  float* pairW = (float*)((char*)d_ws + 512 + NE * NTOK * 4);
  short* xb    = (short*)((char*)d_ws + (size_t)(1)  * (1 << 20));
  short* w1t   = (short*)((char*)d_ws + (size_t)(16) * (1 << 20));
  short* w2t   = (short*)((char*)d_ws + (size_t)(80) * (1 << 20));
  short* h     = (short*)((char*)d_ws + (size_t)(144)* (1 << 20));

  hipMemsetAsync(d_ws, 0, 512, stream);
  hipMemsetAsync(d_out, 0, (size_t)out_size * sizeof(float), stream);

  router_kernel<<<NTOK / 256, 256, 0, stream>>>(x, gw, cnt, psum, pairs, pairW);
  finalize_kernel<<<1, 64, 0, stream>>>(cnt, off, psum, outf + (size_t)NTOK * DM);
  convert_x_kernel<<<NTOK * DM / (256 * 8), 256, 0, stream>>>(x, xb);
  transpose_kernel<<<dim3(64, 16, 16), 256, 0, stream>>>(w1, w2, w1t, w2t);
  gemm1_kernel<<<2048, 512, 0, stream>>>(xb, w1t, cnt, off, pairs, h);
  gemm2_kernel<<<1024, 512, 0, stream>>>(h, w2t, cnt, off, pairs, pairW, outf);
}

// Round 4
// 492.900 us; speedup vs baseline: 1.0749x; 1.0749x over previous
//
#include <hip/hip_runtime.h>
#include <hip/hip_bf16.h>

#define DM   1024
#define NE   8
#define DFF  4096
#define NTOK 4096

typedef __attribute__((ext_vector_type(8))) short bf16x8;
typedef __attribute__((ext_vector_type(4))) float f32x4;

__device__ __forceinline__ short to_bf16(float f) {
  unsigned u = __float_as_uint(f);
  unsigned r = (u + 0x7fffu + ((u >> 16) & 1u)) >> 16;   // RNE
  return (short)r;
}

__device__ __forceinline__ void gl16(const void* g, void* l) {
  __builtin_amdgcn_global_load_lds(
      (const __attribute__((address_space(1))) unsigned*)g,
      (__attribute__((address_space(3))) unsigned*)l, 16, 0, 0);
}

// ---------------- router ----------------
__global__ __launch_bounds__(256) void router_kernel(
    const float* __restrict__ x, const float* __restrict__ gw,
    int* __restrict__ cnt, float* __restrict__ psum,
    int* __restrict__ pairs, float* __restrict__ pairW)
{
  __shared__ float gws[DM * NE];
  const int tid = threadIdx.x;
  for (int i = tid * 4; i < DM * NE; i += 256 * 4)
    *reinterpret_cast<float4*>(&gws[i]) = *reinterpret_cast<const float4*>(&gw[i]);
  __syncthreads();

  const int n = blockIdx.x * 256 + tid;
  float acc[NE];
#pragma unroll
  for (int e = 0; e < NE; ++e) acc[e] = 0.f;

  const float4* xr = reinterpret_cast<const float4*>(x + (size_t)n * DM);
  for (int d4 = 0; d4 < DM / 4; ++d4) {
    float4 v = xr[d4];
    const float* gp = &gws[d4 * 4 * NE];
    float xv;
#pragma unroll
    for (int dd = 0; dd < 4; ++dd) {
      xv = (dd == 0) ? v.x : (dd == 1) ? v.y : (dd == 2) ? v.z : v.w;
#pragma unroll
      for (int e = 0; e < NE; ++e) acc[e] = fmaf(xv, gp[dd * NE + e], acc[e]);
    }
  }

  float mx = acc[0];
#pragma unroll
  for (int e = 1; e < NE; ++e) mx = fmaxf(mx, acc[e]);
  float p[NE], s = 0.f;
#pragma unroll
  for (int e = 0; e < NE; ++e) { p[e] = expf(acc[e] - mx); s += p[e]; }
  float inv = 1.f / s;
#pragma unroll
  for (int e = 0; e < NE; ++e) {
    float v = p[e] * inv;
#pragma unroll
    for (int o = 32; o > 0; o >>= 1) v += __shfl_xor(v, o);
    if ((tid & 63) == 0) atomicAdd(&psum[e], v);
  }

  float v0 = -1e30f, v1 = -1e30f; int i0 = 0, i1 = 0;
#pragma unroll
  for (int e = 0; e < NE; ++e) {
    float l = acc[e];
    if (l > v0) { v1 = v0; i1 = i0; v0 = l; i0 = e; }
    else if (l > v1) { v1 = l; i1 = e; }
  }
  float e1 = expf(v1 - v0);
  float den = 1.f + e1;
  pairW[n * 2]     = 1.f / den;
  pairW[n * 2 + 1] = e1 / den;
  int p0 = atomicAdd(&cnt[i0], 1); pairs[i0 * NTOK + p0] = n * 2;
  int p1 = atomicAdd(&cnt[i1], 1); pairs[i1 * NTOK + p1] = n * 2 + 1;
}

__global__ void finalize_kernel(const int* __restrict__ cnt, int* __restrict__ off,
                                const float* __restrict__ psum, float* __restrict__ aux)
{
  if (threadIdx.x == 0 && blockIdx.x == 0) {
    int o = 0;
    for (int e = 0; e < NE; ++e) { off[e] = o; o += cnt[e]; }
    off[NE] = o;
    float a = 0.f;
    for (int e = 0; e < NE; ++e) { float me = psum[e] * (1.f / NTOK); a += me * me; }
    aux[0] = a * (float)NE;
  }
}

// ---------------- prepass: x f32 -> bf16 ----------------
__global__ __launch_bounds__(256) void convert_x_kernel(
    const float* __restrict__ x, short* __restrict__ xb)
{
  const int i = (blockIdx.x * 256 + threadIdx.x) * 8;
  float4 a = *reinterpret_cast<const float4*>(&x[i]);
  float4 b = *reinterpret_cast<const float4*>(&x[i + 4]);
  union { short s[8]; bf16x8 v; } p;
  p.s[0]=to_bf16(a.x); p.s[1]=to_bf16(a.y); p.s[2]=to_bf16(a.z); p.s[3]=to_bf16(a.w);
  p.s[4]=to_bf16(b.x); p.s[5]=to_bf16(b.y); p.s[6]=to_bf16(b.z); p.s[7]=to_bf16(b.w);
  *reinterpret_cast<bf16x8*>(&xb[i]) = p.v;
}

// ---------------- prepass: transpose + convert weights ----------------
__global__ __launch_bounds__(256) void transpose_kernel(
    const float* __restrict__ w1, const float* __restrict__ w2,
    short* __restrict__ w1t, short* __restrict__ w2t)
{
  const int z = blockIdx.z;
  const float* src; short* dst; int R, C, rt, ct;
  if (z < 8) { src = w1 + (size_t)z * DM * DFF; dst = w1t + (size_t)z * DM * DFF;
               R = DM; C = DFF; ct = blockIdx.x; rt = blockIdx.y; }
  else       { src = w2 + (size_t)(z - 8) * DM * DFF; dst = w2t + (size_t)(z - 8) * DM * DFF;
               R = DFF; C = DM; ct = blockIdx.y; rt = blockIdx.x; }
  const int r0 = rt * 64, c0 = ct * 64;
  __shared__ float t[64][65];
  const int tid = threadIdx.x;
  {
    const int row = tid >> 4;
    const int col = (tid & 15) * 4;
#pragma unroll
    for (int it = 0; it < 4; ++it) {
      float4 v = *reinterpret_cast<const float4*>(&src[(size_t)(r0 + it * 16 + row) * C + c0 + col]);
      t[it * 16 + row][col]     = v.x;
      t[it * 16 + row][col + 1] = v.y;
      t[it * 16 + row][col + 2] = v.z;
      t[it * 16 + row][col + 3] = v.w;
    }
  }
  __syncthreads();
  {
    const int oc  = tid >> 3;
    const int orr = (tid & 7) * 8;
#pragma unroll
    for (int it = 0; it < 2; ++it) {
      union { short s[8]; bf16x8 v; } p;
#pragma unroll
      for (int j = 0; j < 8; ++j) p.s[j] = to_bf16(t[orr + j][it * 32 + oc]);
      *reinterpret_cast<bf16x8*>(&dst[(size_t)(c0 + it * 32 + oc) * R + r0 + orr]) = p.v;
    }
  }
}

// LDS swizzle (BK=32): view tile as [64 pairs][8 chunks of 8 shorts];
// LDS chunk (p,s) holds global (row = 2p + ((s^(p&7))>>2), kchunk = (s^(p&7))&3).
// Reads: lane wants (row, kc=lane>>4) -> s = (((row&1)<<2)|kc) ^ ((row>>1)&7).

// ======== GEMM1: h = gelu(gather(xb) @ w1t[e]^T), 128x128xBK32, dbuf 1-barrier ========
__global__ __launch_bounds__(256) void gemm1_kernel(
    const short* __restrict__ xb, const short* __restrict__ w1t,
    const int* __restrict__ cnt, const int* __restrict__ off,
    const int* __restrict__ pairs, short* __restrict__ h)
{
  // bijective XCD swizzle, nwg=8192; decode: m inner(32), e mid(8), ff outer(32)
  const int wg = (blockIdx.x & 7) * 1024 + (blockIdx.x >> 3);
  const int mt  = wg & 31;
  const int e   = (wg >> 5) & 7;
  const int ft  = wg >> 8;
  const int M   = cnt[e];
  const int m0  = mt * 128;
  if (m0 >= M) return;
  const int ff0  = ft * 128;
  const int base = off[e];

  __shared__ __attribute__((aligned(16))) short As[2][128 * 32];
  __shared__ __attribute__((aligned(16))) short Bs[2][128 * 32];

  const int tid  = threadIdx.x;
  const int lane = tid & 63;
  const int wv   = tid >> 6;
  const int wm   = wv >> 1;   // 0..1
  const int wn   = wv & 1;    // 0..1

  // staging: 2 chunk-slots per thread per operand
  const short* gA[2]; const short* gB[2]; int ldo[2];
#pragma unroll
  for (int l = 0; l < 2; ++l) {
    const int n   = l * 256 + tid;          // 0..511
    const int p   = n >> 3;
    const int s   = n & 7;
    const int cip = s ^ (p & 7);
    const int row = p * 2 + (cip >> 2);     // 0..127
    const int kch = cip & 3;
    int gi = m0 + row; if (gi > M - 1) gi = M - 1;
    const int tok = pairs[e * NTOK + gi] >> 1;
    gA[l]  = xb + (size_t)tok * DM + kch * 8;
    gB[l]  = w1t + ((size_t)e * DFF + ff0 + row) * DM + kch * 8;
    ldo[l] = n * 8;                          // shorts
  }

#define STAGE1(buf, k0) do { \
  gl16(gA[0] + (k0), &As[buf][ldo[0]]); \
  gl16(gA[1] + (k0), &As[buf][ldo[1]]); \
  gl16(gB[0] + (k0), &Bs[buf][ldo[0]]); \
  gl16(gB[1] + (k0), &Bs[buf][ldo[1]]); \
} while (0)

  // read offsets
  const int lrw = lane & 15;
  const int sr  = ((((lane & 1) << 2) | (lane >> 4)) ^ ((lane & 15) >> 1)) * 8;
  const int ab  = (wm * 32 + (lrw >> 1)) * 64 + sr;   // + i*512
  const int bb  = (wn * 32 + (lrw >> 1)) * 64 + sr;   // + j*512

  f32x4 acc[4][4];
#pragma unroll
  for (int i = 0; i < 4; ++i)
#pragma unroll
    for (int j = 0; j < 4; ++j) acc[i][j] = (f32x4){0.f, 0.f, 0.f, 0.f};

  STAGE1(0, 0);
  __syncthreads();

  for (int t = 0; t < 32; ++t) {
    const int cur = t & 1;
    if (t < 31) STAGE1(cur ^ 1, (t + 1) * 32);
    bf16x8 af[4], bfv[4];
#pragma unroll
    for (int i = 0; i < 4; ++i)
      af[i] = *reinterpret_cast<const bf16x8*>(&As[cur][ab + i * 512]);
#pragma unroll
    for (int j = 0; j < 4; ++j)
      bfv[j] = *reinterpret_cast<const bf16x8*>(&Bs[cur][bb + j * 512]);
#pragma unroll
    for (int i = 0; i < 4; ++i)
#pragma unroll
      for (int j = 0; j < 4; ++j)
        acc[i][j] = __builtin_amdgcn_mfma_f32_16x16x32_bf16(af[i], bfv[j], acc[i][j], 0, 0, 0);
    __syncthreads();
  }

  const int erow0 = m0 + wm * 64 + (lane >> 4) * 4;
  const int ecol0 = ff0 + wn * 64 + (lane & 15);
#pragma unroll
  for (int i = 0; i < 4; ++i) {
#pragma unroll
    for (int r = 0; r < 4; ++r) {
      const int grow = erow0 + i * 16 + r;
      if (grow < M) {
#pragma unroll
        for (int j = 0; j < 4; ++j) {
          float v = acc[i][j][r];
          float g = 0.5f * v * (1.f + erff(v * 0.70710678118f));
          h[(size_t)(base + grow) * DFF + ecol0 + j * 16] = to_bf16(g);
        }
      }
    }
  }
#undef STAGE1
}

// ======== GEMM2: out += w * (h @ w2t[e]^T), 128x128xBK32, split-K=2, dbuf ========
__global__ __launch_bounds__(256) void gemm2_kernel(
    const short* __restrict__ h, const short* __restrict__ w2t,
    const int* __restrict__ cnt, const int* __restrict__ off,
    const int* __restrict__ pairs, const float* __restrict__ pairW,
    float* __restrict__ out)
{
  // nwg=4096; decode: m inner(32), e mid(8), (dt,kh) outer(16)
  const int wg = (blockIdx.x & 7) * 512 + (blockIdx.x >> 3);
  const int mt = wg & 31;
  const int e  = (wg >> 5) & 7;
  const int z  = wg >> 8;          // 0..15
  const int dt = z & 7;
  const int kh = z >> 3;           // 0..1
  const int M  = cnt[e];
  const int m0 = mt * 128;
  if (m0 >= M) return;
  const int d0    = dt * 128;
  const int kbase = kh * 2048;
  const int base  = off[e];

  __shared__ __attribute__((aligned(16))) short As[2][128 * 32];
  __shared__ __attribute__((aligned(16))) short Bs[2][128 * 32];

  const int tid  = threadIdx.x;
  const int lane = tid & 63;
  const int wv   = tid >> 6;
  const int wm   = wv >> 1;
  const int wn   = wv & 1;

  const short* gA[2]; const short* gB[2]; int ldo[2];
#pragma unroll
  for (int l = 0; l < 2; ++l) {
    const int n   = l * 256 + tid;
    const int p   = n >> 3;
    const int s   = n & 7;
    const int cip = s ^ (p & 7);
    const int row = p * 2 + (cip >> 2);
    const int kch = cip & 3;
    int gi = m0 + row; if (gi > M - 1) gi = M - 1;
    gA[l]  = h + (size_t)(base + gi) * DFF + kbase + kch * 8;
    gB[l]  = w2t + ((size_t)e * DM + d0 + row) * DFF + kbase + kch * 8;
    ldo[l] = n * 8;
  }

#define STAGE2(buf, k0) do { \
  gl16(gA[0] + (k0), &As[buf][ldo[0]]); \
  gl16(gA[1] + (k0), &As[buf][ldo[1]]); \
  gl16(gB[0] + (k0), &Bs[buf][ldo[0]]); \
  gl16(gB[1] + (k0), &Bs[buf][ldo[1]]); \
} while (0)

  const int lrw = lane & 15;
  const int sr  = ((((lane & 1) << 2) | (lane >> 4)) ^ ((lane & 15) >> 1)) * 8;
  const int ab  = (wm * 32 + (lrw >> 1)) * 64 + sr;
  const int bb  = (wn * 32 + (lrw >> 1)) * 64 + sr;

  f32x4 acc[4][4];
#pragma unroll
  for (int i = 0; i < 4; ++i)
#pragma unroll
    for (int j = 0; j < 4; ++j) acc[i][j] = (f32x4){0.f, 0.f, 0.f, 0.f};

  STAGE2(0, 0);
  __syncthreads();

  for (int t = 0; t < 64; ++t) {
    const int cur = t & 1;
    if (t < 63) STAGE2(cur ^ 1, (t + 1) * 32);
    bf16x8 af[4], bfv[4];
#pragma unroll
    for (int i = 0; i < 4; ++i)
      af[i] = *reinterpret_cast<const bf16x8*>(&As[cur][ab + i * 512]);
#pragma unroll
    for (int j = 0; j < 4; ++j)
      bfv[j] = *reinterpret_cast<const bf16x8*>(&Bs[cur][bb + j * 512]);
#pragma unroll
    for (int i = 0; i < 4; ++i)
#pragma unroll
      for (int j = 0; j < 4; ++j)
        acc[i][j] = __builtin_amdgcn_mfma_f32_16x16x32_bf16(af[i], bfv[j], acc[i][j], 0, 0, 0);
    __syncthreads();
  }

  const int erow0 = m0 + wm * 64 + (lane >> 4) * 4;
  const int ecol0 = d0 + wn * 64 + (lane & 15);
#pragma unroll
  for (int i = 0; i < 4; ++i) {
#pragma unroll
    for (int r = 0; r < 4; ++r) {
      const int grow = erow0 + i * 16 + r;
      if (grow < M) {
        const int pr    = pairs[e * NTOK + grow];
        const float wgt = pairW[pr];
        const int tok   = pr >> 1;
#pragma unroll
        for (int j = 0; j < 4; ++j)
          atomicAdd(&out[(size_t)tok * DM + ecol0 + j * 16], wgt * acc[i][j][r]);
      }
    }
  }
#undef STAGE2
}

extern "C" void kernel_launch(void* const* d_in, const int* in_sizes, int n_in,
                              void* d_out, int out_size, void* d_ws, size_t ws_size,
                              hipStream_t stream)
{
  const float* x  = (const float*)d_in[0];
  const float* gw = (const float*)d_in[1];
  const float* w1 = (const float*)d_in[2];
  const float* w2 = (const float*)d_in[3];
  float* outf = (float*)d_out;

  int*   cnt   = (int*)d_ws;
  int*   off   = cnt + 8;
  float* psum  = (float*)(cnt + 20);
  int*   pairs = (int*)((char*)d_ws + 512);
  float* pairW = (float*)((char*)d_ws + 512 + NE * NTOK * 4);
  short* xb    = (short*)((char*)d_ws + (size_t)(1)  * (1 << 20));
  short* w1t   = (short*)((char*)d_ws + (size_t)(16) * (1 << 20));
  short* w2t   = (short*)((char*)d_ws + (size_t)(80) * (1 << 20));
  short* h     = (short*)((char*)d_ws + (size_t)(144)* (1 << 20));

  hipMemsetAsync(d_ws, 0, 512, stream);
  hipMemsetAsync(d_out, 0, (size_t)out_size * sizeof(float), stream);

  router_kernel<<<NTOK / 256, 256, 0, stream>>>(x, gw, cnt, psum, pairs, pairW);
  finalize_kernel<<<1, 64, 0, stream>>>(cnt, off, psum, outf + (size_t)NTOK * DM);
  convert_x_kernel<<<NTOK * DM / (256 * 8), 256, 0, stream>>>(x, xb);
  transpose_kernel<<<dim3(64, 16, 16), 256, 0, stream>>>(w1, w2, w1t, w2t);
  gemm1_kernel<<<8192, 256, 0, stream>>>(xb, w1t, cnt, off, pairs, h);
  gemm2_kernel<<<4096, 256, 0, stream>>>(h, w2t, cnt, off, pairs, pairW, outf);
}